// Round 20
// baseline (230.113 us; speedup 1.0000x reference)
//
#include <hip/hip_runtime.h>
#include <hip/hip_bf16.h>
#include <stdint.h>

#define Bb 4
#define Ss 2048
#define Dd 1024
#define Hh 16
#define DK 64
#define BH 64
#define Mm 8192

typedef __attribute__((ext_vector_type(8))) _Float16 f16x8;
typedef __attribute__((ext_vector_type(4))) _Float16 f16x4;
typedef __attribute__((ext_vector_type(2))) __fp16 fp16x2;
typedef __attribute__((ext_vector_type(4))) float f32x4;
typedef __attribute__((ext_vector_type(16))) float f32x16;
typedef __attribute__((ext_vector_type(2))) unsigned uint2v;

__device__ __forceinline__ void gload16(const _Float16* g, _Float16* lds) {
  __builtin_amdgcn_global_load_lds((const __attribute__((address_space(1))) unsigned int*)g,
                                   (__attribute__((address_space(3))) unsigned int*)lds, 16, 0, 0);
}

// single v_exp_f32 (2^x). exp2f() is the libm path — the r11 regression.
#if __has_builtin(__builtin_amdgcn_exp2f)
__device__ __forceinline__ float ex2(float x) { return __builtin_amdgcn_exp2f(x); }
#else
__device__ __forceinline__ float ex2(float x) {
  float r; asm("v_exp_f32 %0, %1" : "=v"(r) : "v"(x)); return r;
}
#endif

// pack two f32 -> u32 of 2 f16 (v_cvt_pkrtz_f16_f32, 1 inst)
__device__ __forceinline__ unsigned pk2u(float a, float b) {
  union { fp16x2 h; unsigned u; } x;
  x.h = __builtin_amdgcn_cvt_pkrtz(a, b);
  return x.u;
}

// cross-half (lane ^ 32) max via permlane32_swap (VALU, not ds_bpermute)
__device__ __forceinline__ float xhalf_max(float x) {
  union { float f; unsigned u; } a; a.f = x;
  uint2v r = __builtin_amdgcn_permlane32_swap(a.u, a.u, false, false);
  union { unsigned u; float f; } b0, b1; b0.u = r[0]; b1.u = r[1];
  return fmaxf(fmaxf(x, b0.f), b1.f);
}

// counted vmcnt + scheduling fence (rule #18)
#define VW(N)                                                           \
  do {                                                                  \
    asm volatile("s_waitcnt vmcnt(" #N ")" ::: "memory");               \
    __builtin_amdgcn_sched_barrier(0);                                  \
  } while (0)

// ---------------- K0b: convert + transpose weights: Wt[n][k] = f16(W[k][n]) ----------------
// Q weights pre-scaled by log2(e): attention scores land in the exp2 domain.
__global__ __launch_bounds__(256) void cvt_wt(const float* __restrict__ wq,
                                              const float* __restrict__ wk,
                                              const float* __restrict__ wv,
                                              _Float16* __restrict__ tq,
                                              _Float16* __restrict__ tk,
                                              _Float16* __restrict__ tv) {
  const float* w = blockIdx.z == 0 ? wq : (blockIdx.z == 1 ? wk : wv);
  _Float16* o = blockIdx.z == 0 ? tq : (blockIdx.z == 1 ? tk : tv);
  float wscale = blockIdx.z == 0 ? 1.4426950408889634f : 1.0f;
  __shared__ float tile[64][65];
  int k0 = blockIdx.x * 64;
  int n0 = blockIdx.y * 64;
  int t = threadIdx.x;
  int tr = t >> 4;
  int tc = (t & 15) * 4;
  for (int i = 0; i < 4; i++) {
    int r = i * 16 + tr;
    float4 val = *(const float4*)(w + (k0 + r) * Dd + n0 + tc);
    tile[r][tc + 0] = val.x; tile[r][tc + 1] = val.y;
    tile[r][tc + 2] = val.z; tile[r][tc + 3] = val.w;
  }
  __syncthreads();
  for (int i = 0; i < 2; i++) {
    int vdx = t + 256 * i;
    int rn = vdx >> 3;
    int c8 = (vdx & 7) * 8;
    union { f16x8 v8; _Float16 h[8]; } o2;
    for (int j = 0; j < 8; j++) o2.h[j] = (_Float16)(tile[c8 + j][rn] * wscale);
    *(f16x8*)(o + (n0 + rn) * Dd + k0 + c8) = o2.v8;
  }
}

// ---------------- K1: projection GEMM — double-buffered + XOR-swizzled LDS (r19, ~72us) ----------------
__global__ __launch_bounds__(256) void gemm_qkv(
    const float* __restrict__ aq, const float* __restrict__ ak,
    const float* __restrict__ av,
    const _Float16* __restrict__ wtq, const _Float16* __restrict__ wtk,
    const _Float16* __restrict__ wtv,
    const float* __restrict__ bq, const float* __restrict__ bk, const float* __restrict__ bv,
    _Float16* __restrict__ oq, _Float16* __restrict__ ok,
    _Float16* __restrict__ ov) {
  int z = blockIdx.z;
  const float* Af    = z == 0 ? aq  : (z == 1 ? ak  : av);
  const _Float16* Bt = z == 0 ? wtq : (z == 1 ? wtk : wtv);
  const float* bias  = z == 0 ? bq  : (z == 1 ? bk  : bv);
  _Float16* out      = z == 0 ? oq  : (z == 1 ? ok  : ov);
  float bscale       = z == 0 ? 1.4426950408889634f : 1.0f;

  __shared__ _Float16 As[2][128 * 64];
  __shared__ _Float16 Bs[2][128 * 64];

  int tid = threadIdx.x;
  int w = tid >> 6;
  int l = tid & 63;
  int lr = l & 15, lk = l >> 4;
  int m0 = blockIdx.x * 128;
  int n0 = blockIdx.y * 128;
  int wr = (w >> 1) * 64;
  int wc = (w & 1) * 64;

  int srow = l >> 3;
  int cs = (l & 7) ^ srow;
  const float*    ap[4];
  const _Float16* bp[4];
#pragma unroll
  for (int i = 0; i < 4; i++) {
    int row = i * 32 + w * 8 + srow;
    ap[i] = Af + (size_t)(m0 + row) * Dd + cs * 8;
    bp[i] = Bt + (size_t)(n0 + row) * Dd + cs * 8;
  }

  f32x4 acc[4][4] = {};
  int lr7 = lr & 7;
  int rs0 = (lk ^ lr7) * 8;
  int rs1 = ((4 + lk) ^ lr7) * 8;

#define ALOAD(AR)                                                         \
  _Pragma("unroll")                                                       \
  for (int i = 0; i < 4; i++) {                                           \
    AR[i][0] = *(const float4*)(ap[i]);                                   \
    AR[i][1] = *(const float4*)(ap[i] + 4);                               \
    ap[i] += 64;                                                          \
  }
#define BDMA(NXT)                                                         \
  _Pragma("unroll")                                                       \
  for (int i = 0; i < 4; i++) {                                           \
    gload16(bp[i], &Bs[NXT][(i * 256 + w * 64) * 8]);                     \
    bp[i] += 64;                                                          \
  }
#define AWRITE(AR, NXT)                                                   \
  _Pragma("unroll")                                                       \
  for (int i = 0; i < 4; i++) {                                           \
    union { unsigned u[4]; f16x8 v; } aw;                                 \
    aw.u[0] = pk2u(AR[i][0].x, AR[i][0].y);                               \
    aw.u[1] = pk2u(AR[i][0].z, AR[i][0].w);                               \
    aw.u[2] = pk2u(AR[i][1].x, AR[i][1].y);                               \
    aw.u[3] = pk2u(AR[i][1].z, AR[i][1].w);                               \
    *(f16x8*)&As[NXT][(i * 256 + w * 64 + l) * 8] = aw.v;                 \
  }
#define GCOMP(CUR)                                                              \
  _Pragma("unroll")                                                             \
  for (int kh = 0; kh < 2; kh++) {                                              \
    int rs = kh ? rs1 : rs0;                                                    \
    f16x8 af[4], bf[4];                                                         \
    _Pragma("unroll")                                                           \
    for (int mi = 0; mi < 4; mi++)                                              \
      af[mi] = *(const f16x8*)&As[CUR][(wr + mi * 16 + lr) * 64 + rs];          \
    _Pragma("unroll")                                                           \
    for (int ni = 0; ni < 4; ni++)                                              \
      bf[ni] = *(const f16x8*)&Bs[CUR][(wc + ni * 16 + lr) * 64 + rs];          \
    _Pragma("unroll")                                                           \
    for (int mi = 0; mi < 4; mi++)                                              \
      _Pragma("unroll")                                                         \
      for (int ni = 0; ni < 4; ni++)                                            \
        acc[mi][ni] = __builtin_amdgcn_mfma_f32_16x16x32_f16(af[mi], bf[ni], acc[mi][ni], 0, 0, 0); \
  }

  {
    float4 ar[4][2];
    ALOAD(ar)
    BDMA(0)
    AWRITE(ar, 0)
  }
  __syncthreads();

  for (int it = 0; it < 7; ++it) {
    {
      float4 ar[4][2];
      ALOAD(ar)
      BDMA(1)
      GCOMP(0)
      AWRITE(ar, 1)
    }
    __syncthreads();
    {
      float4 ar[4][2];
      ALOAD(ar)
      BDMA(0)
      GCOMP(1)
      AWRITE(ar, 0)
    }
    __syncthreads();
  }
  {
    float4 ar[4][2];
    ALOAD(ar)
    BDMA(1)
    GCOMP(0)
    AWRITE(ar, 1)
  }
  __syncthreads();
  GCOMP(1)
#undef GCOMP
#undef AWRITE
#undef BDMA
#undef ALOAD

  if (z == 2) {
    for (int mi = 0; mi < 4; mi++) {
      for (int ni = 0; ni < 4; ni++) {
        int n = n0 + wc + ni * 16 + lr;
        float bval = bias[n];
        int h = n >> 6, dk = n & 63;
        int m = m0 + wr + mi * 16 + lk * 4;
        int b = m >> 11, s = m & 2047;
        f16x4 o4;
        for (int j = 0; j < 4; j++) o4[j] = (_Float16)(acc[mi][ni][j] + bval);
        *(f16x4*)(out + ((size_t)((b * Hh + h) * DK + dk) * Ss + s)) = o4;
      }
    }
  } else {
    for (int mi = 0; mi < 4; mi++) {
      for (int ni = 0; ni < 4; ni++) {
        int n = n0 + wc + ni * 16 + lr;
        float bval = bias[n] * bscale;
        int h = n >> 6, dk = n & 63;
        for (int j = 0; j < 4; j++) {
          int m = m0 + wr + mi * 16 + lk * 4 + j;
          int b = m >> 11, s = m & 2047;
          out[((b * Hh + h) * Ss + s) * DK + dk] = (_Float16)(acc[mi][ni][j] + bval);
        }
      }
    }
  }
}

// ---------------- K3: flash attention — 1-wave blocks, barrier-free, counted vmcnt ----------------
// Q,K: [bh][s][64] f16 (Q pre-scaled by log2e); Vt: [bh][64][s] f16; out fp32 = ctx + query.
// 4096 blocks x 1 wave (64 thr); wave owns 32 q-rows, kv-tile 32, wave-PRIVATE double-buffered
// LDS (16KB/block -> ~10 independent waves/CU vs 6 effective before). NO barriers: RAW on the
// global_load_lds DMA is enforced by counted s_waitcnt vmcnt(8)/(0) (T3/T4; the intrinsic is
// compiler-tracked, unlike r9's raw asm loads). setprio around MFMA clusters (independent
// waves = T5-positive regime, m191). Swizzles: K slot^(row&7) (as r17); V 64B rows,
// slot^((d>>1)&3), write-source/read involution verified.
__global__ __launch_bounds__(64) void attn(const _Float16* __restrict__ Qb,
                                           const _Float16* __restrict__ Kb,
                                           const _Float16* __restrict__ Vt,
                                           const float* __restrict__ query,
                                           float* __restrict__ outp) {
  __shared__ _Float16 Kl[2][32 * 64];   // 4KB per buf
  __shared__ _Float16 Vl[2][64 * 32];   // 4KB per buf

  int l = threadIdx.x;
  int l31 = l & 31, hi = l >> 5;
  int bh = blockIdx.x;                  // same-bh blocks land on the same XCD (stride 64 in flat id)
  int q0 = blockIdx.y * 32;
  const _Float16* Qp = Qb + bh * (Ss * DK);
  const _Float16* Kp = Kb + bh * (Ss * DK);
  const _Float16* Vp = Vt + bh * (DK * Ss);

  // K staging: instr j covers rows j*8+(l>>3); LDS slot l&7; source col (l&7)^(l>>3)
  int kr = l >> 3;
  int kcs = (l & 7) ^ kr;
  const _Float16* kpA = Kp + (kr + 0)  * DK + kcs * 8;
  const _Float16* kpB = Kp + (kr + 8)  * DK + kcs * 8;
  const _Float16* kpC = Kp + (kr + 16) * DK + kcs * 8;
  const _Float16* kpD = Kp + (kr + 24) * DK + kcs * 8;
  // V staging: instr j covers rows j*16+(l>>2); LDS slot l&3; source col (l&3)^((l>>3)&3)
  int vr = l >> 2;
  int vcs = (l & 3) ^ ((l >> 3) & 3);
  const _Float16* vpA = Vp + (vr + 0)  * Ss + vcs * 8;
  const _Float16* vpB = Vp + (vr + 16) * Ss + vcs * 8;
  const _Float16* vpC = Vp + (vr + 32) * Ss + vcs * 8;
  const _Float16* vpD = Vp + (vr + 48) * Ss + vcs * 8;

#define STAGE(B)                                                          \
  {                                                                       \
    gload16(kpA, &Kl[B][0 * 512]); gload16(kpB, &Kl[B][1 * 512]);         \
    gload16(kpC, &Kl[B][2 * 512]); gload16(kpD, &Kl[B][3 * 512]);         \
    gload16(vpA, &Vl[B][0 * 512]); gload16(vpB, &Vl[B][1 * 512]);         \
    gload16(vpC, &Vl[B][2 * 512]); gload16(vpD, &Vl[B][3 * 512]);         \
    kpA += 32 * DK; kpB += 32 * DK; kpC += 32 * DK; kpD += 32 * DK;       \
    vpA += 32; vpB += 32; vpC += 32; vpD += 32;                           \
  }

  // Q as B-operand: col=q=q0+l31, k=dk=s*16+hi*8+i
  f16x8 qf[4];
#pragma unroll
  for (int s = 0; s < 4; s++)
    qf[s] = *(const f16x8*)(Qp + (q0 + l31) * DK + s * 16 + hi * 8);

  f32x16 o0 = {}, o1 = {};    // ctx^T: row d=dg*32+(r&3)+8*(r>>2)+4*hi, col q=l31
  float mrun = -1e30f, lrun = 0.f;   // lrun lane-partial

  // K read slots (row l31): ((s*2+hi) ^ (l31&7)) * 8
  int kv7 = l31 & 7;
  int rslot[4];
#pragma unroll
  for (int s = 0; s < 4; s++) rslot[s] = ((s * 2 + hi) ^ kv7) * 8;
  // V read slots (rows l31 and 32+l31 share (d>>1)&3 = (l31>>1)&3)
  int vsw = (l31 >> 1) & 3;
  int vslot0 = ((0 * 2 + hi) ^ vsw) * 8;
  int vslot1 = ((1 * 2 + hi) ^ vsw) * 8;

#define PVST(B, OFF, VSL)                                                       \
    {                                                                           \
      unsigned a0 = pk2u(s0[(OFF) + 0], s0[(OFF) + 1]);                         \
      unsigned a1 = pk2u(s0[(OFF) + 2], s0[(OFF) + 3]);                         \
      unsigned b0 = pk2u(s0[(OFF) + 4], s0[(OFF) + 5]);                         \
      unsigned b1 = pk2u(s0[(OFF) + 6], s0[(OFF) + 7]);                         \
      uint2v r0 = __builtin_amdgcn_permlane32_swap(a0, b0, false, false);       \
      uint2v r1 = __builtin_amdgcn_permlane32_swap(a1, b1, false, false);       \
      union { unsigned u[4]; f16x8 v; } pf;                                     \
      pf.u[0] = r0[0]; pf.u[1] = r1[0]; pf.u[2] = r0[1]; pf.u[3] = r1[1];       \
      f16x8 v0 = *(const f16x8*)&Vl[B][l31 * 32 + (VSL)];                       \
      f16x8 v1 = *(const f16x8*)&Vl[B][(32 + l31) * 32 + (VSL)];                \
      o0 = __builtin_amdgcn_mfma_f32_32x32x16_f16(v0, pf.v, o0, 0, 0, 0);       \
      o1 = __builtin_amdgcn_mfma_f32_32x32x16_f16(v1, pf.v, o1, 0, 0, 0);       \
    }

#define TILE(B)                                                                 \
  {                                                                             \
    f32x16 s0 = {};                                                             \
    __builtin_amdgcn_s_setprio(1);                                              \
    _Pragma("unroll")                                                           \
    for (int s = 0; s < 4; s++) {                                               \
      f16x8 ka = *(const f16x8*)&Kl[B][l31 * 64 + rslot[s]];                    \
      s0 = __builtin_amdgcn_mfma_f32_32x32x16_f16(ka, qf[s], s0, 0, 0, 0);      \
    }                                                                           \
    __builtin_amdgcn_s_setprio(0);                                              \
    float m8[8];                                                                \
    _Pragma("unroll")                                                           \
    for (int r = 0; r < 8; r++) m8[r] = fmaxf(s0[r], s0[r + 8]);                \
    _Pragma("unroll")                                                           \
    for (int d = 4; d >= 1; d >>= 1)                                            \
      for (int r = 0; r < 4; r++) if (r < d) m8[r] = fmaxf(m8[r], m8[r + d]);   \
    float pm = xhalf_max(m8[0]);                                                \
    if (!__all(pm - mrun <= 8.f)) {   /* defer-max (T13), log2 units */         \
      float mn = fmaxf(mrun, pm);                                               \
      float sc_ = ex2(mrun - mn);                                               \
      mrun = mn;                                                                \
      lrun *= sc_;                                                              \
      _Pragma("unroll")                                                         \
      for (int r = 0; r < 16; r++) { o0[r] *= sc_; o1[r] *= sc_; }              \
    }                                                                           \
    _Pragma("unroll")                                                           \
    for (int r = 0; r < 16; r++) s0[r] = ex2(s0[r] - mrun);                     \
    float s8[8];                                                                \
    _Pragma("unroll")                                                           \
    for (int r = 0; r < 8; r++) s8[r] = s0[r] + s0[r + 8];                      \
    _Pragma("unroll")                                                           \
    for (int d = 4; d >= 1; d >>= 1)                                            \
      for (int r = 0; r < 4; r++) if (r < d) s8[r] += s8[r + d];                \
    lrun += s8[0];                                                              \
    __builtin_amdgcn_s_setprio(1);                                              \
    PVST(B, 0, vslot0)                                                          \
    PVST(B, 8, vslot1)                                                          \
    __builtin_amdgcn_s_setprio(0);                                              \
  }

  // prologue: stage tiles 0,1 (16 DMA + 4 qf loads in flight)
  STAGE(0)
  STAGE(1)
  VW(8);      // qf + tile0 complete; tile1's 8 may be in flight

  for (int it = 0; it < 31; ++it) {
    TILE(0)           // tile 2*it
    STAGE(0)          // tile 2*it+2
    VW(8);            // tile 2*it+1 complete
    TILE(1)           // tile 2*it+1
    STAGE(1)          // tile 2*it+3
    VW(8);            // tile 2*it+2 complete
  }
  TILE(0)             // tile 62
  VW(0);              // tile 63 complete
  TILE(1)             // tile 63
#undef TILE
#undef PVST
#undef STAGE

  // ---- epilogue: reduce lane-partial lrun, normalize, add residual ----
  lrun += __shfl_xor(lrun, 32);
  int b = bh >> 4, h = bh & 15;
  float inv = 1.f / lrun;
  int base = (b * Ss + q0 + l31) * Dd + h * 64;
#pragma unroll
  for (int rq = 0; rq < 4; rq++) {
    int d0 = rq * 8 + hi * 4;
    float4 qv0 = *(const float4*)(query + base + d0);
    float4 ov0;
    ov0.x = o0[rq * 4 + 0] * inv + qv0.x;
    ov0.y = o0[rq * 4 + 1] * inv + qv0.y;
    ov0.z = o0[rq * 4 + 2] * inv + qv0.z;
    ov0.w = o0[rq * 4 + 3] * inv + qv0.w;
    *(float4*)(outp + base + d0) = ov0;
    float4 qv1 = *(const float4*)(query + base + 32 + d0);
    float4 ov1;
    ov1.x = o1[rq * 4 + 0] * inv + qv1.x;
    ov1.y = o1[rq * 4 + 1] * inv + qv1.y;
    ov1.z = o1[rq * 4 + 2] * inv + qv1.z;
    ov1.w = o1[rq * 4 + 3] * inv + qv1.w;
    *(float4*)(outp + base + 32 + d0) = ov1;
  }
}

extern "C" void kernel_launch(void* const* d_in, const int* in_sizes, int n_in,
                              void* d_out, int out_size, void* d_ws, size_t ws_size,
                              hipStream_t stream) {
  const float* query = (const float*)d_in[0];
  const float* key   = (const float*)d_in[1];
  const float* value = (const float*)d_in[2];
  const float* Wq = (const float*)d_in[3];
  const float* bq = (const float*)d_in[4];
  const float* Wk = (const float*)d_in[5];
  const float* bk = (const float*)d_in[6];
  const float* Wv = (const float*)d_in[7];
  const float* bv = (const float*)d_in[8];
  float* out = (float*)d_out;

  _Float16* ws = (_Float16*)d_ws;
  const size_t ACT = (size_t)Mm * Dd;
  const size_t WSZ = (size_t)Dd * Dd;
  _Float16* Wtq  = ws;
  _Float16* Wtk  = Wtq + WSZ;
  _Float16* Wtv  = Wtk + WSZ;
  _Float16* Qb   = Wtv + WSZ;
  _Float16* Kb   = Qb + ACT;
  _Float16* VtT  = Kb + ACT;   // gemm writes V^T [bh][dk][s] here directly

  cvt_wt<<<dim3(16, 16, 3), dim3(256), 0, stream>>>(Wq, Wk, Wv, Wtq, Wtk, Wtv);
  gemm_qkv<<<dim3(64, 8, 3), dim3(256), 0, stream>>>(query, key, value, Wtq, Wtk, Wtv,
                                                     bq, bk, bv, Qb, Kb, VtT);
  attn<<<dim3(64, 64), dim3(64), 0, stream>>>(Qb, Kb, VtT, query, out);
}

// Round 21
// 200.391 us; speedup vs baseline: 1.1483x; 1.1483x over previous
//
#include <hip/hip_runtime.h>
#include <hip/hip_bf16.h>
#include <stdint.h>

#define Bb 4
#define Ss 2048
#define Dd 1024
#define Hh 16
#define DK 64
#define BH 64
#define Mm 8192
#define KVT 64

typedef __attribute__((ext_vector_type(8))) _Float16 f16x8;
typedef __attribute__((ext_vector_type(4))) _Float16 f16x4;
typedef __attribute__((ext_vector_type(2))) __fp16 fp16x2;
typedef __attribute__((ext_vector_type(4))) float f32x4;
typedef __attribute__((ext_vector_type(16))) float f32x16;
typedef __attribute__((ext_vector_type(2))) unsigned uint2v;

__device__ __forceinline__ void gload16(const _Float16* g, _Float16* lds) {
  __builtin_amdgcn_global_load_lds((const __attribute__((address_space(1))) unsigned int*)g,
                                   (__attribute__((address_space(3))) unsigned int*)lds, 16, 0, 0);
}

// single v_exp_f32 (2^x). exp2f() is the libm path — the r11 regression.
#if __has_builtin(__builtin_amdgcn_exp2f)
__device__ __forceinline__ float ex2(float x) { return __builtin_amdgcn_exp2f(x); }
#else
__device__ __forceinline__ float ex2(float x) {
  float r; asm("v_exp_f32 %0, %1" : "=v"(r) : "v"(x)); return r;
}
#endif

// pack two f32 -> u32 of 2 f16 (v_cvt_pkrtz_f16_f32, 1 inst)
__device__ __forceinline__ unsigned pk2u(float a, float b) {
  union { fp16x2 h; unsigned u; } x;
  x.h = __builtin_amdgcn_cvt_pkrtz(a, b);
  return x.u;
}

// cross-half (lane ^ 32) max via permlane32_swap (VALU, not ds_bpermute)
__device__ __forceinline__ float xhalf_max(float x) {
  union { float f; unsigned u; } a; a.f = x;
  uint2v r = __builtin_amdgcn_permlane32_swap(a.u, a.u, false, false);
  union { unsigned u; float f; } b0, b1; b0.u = r[0]; b1.u = r[1];
  return fmaxf(fmaxf(x, b0.f), b1.f);
}

// counted vmcnt + scheduling fence (rule #18)
#define VW(N)                                                           \
  do {                                                                  \
    asm volatile("s_waitcnt vmcnt(" #N ")" ::: "memory");               \
    __builtin_amdgcn_sched_barrier(0);                                  \
  } while (0)
// raw workgroup barrier (no implicit vmcnt(0) drain) + scheduling fence
#define BAR()                                                           \
  do {                                                                  \
    __builtin_amdgcn_s_barrier();                                       \
    __builtin_amdgcn_sched_barrier(0);                                  \
  } while (0)

// ---------------- K0b: convert + transpose weights: Wt[n][k] = f16(W[k][n]) ----------------
// Q weights pre-scaled by log2(e): attention scores land in the exp2 domain.
__global__ __launch_bounds__(256) void cvt_wt(const float* __restrict__ wq,
                                              const float* __restrict__ wk,
                                              const float* __restrict__ wv,
                                              _Float16* __restrict__ tq,
                                              _Float16* __restrict__ tk,
                                              _Float16* __restrict__ tv) {
  const float* w = blockIdx.z == 0 ? wq : (blockIdx.z == 1 ? wk : wv);
  _Float16* o = blockIdx.z == 0 ? tq : (blockIdx.z == 1 ? tk : tv);
  float wscale = blockIdx.z == 0 ? 1.4426950408889634f : 1.0f;
  __shared__ float tile[64][65];
  int k0 = blockIdx.x * 64;
  int n0 = blockIdx.y * 64;
  int t = threadIdx.x;
  int tr = t >> 4;
  int tc = (t & 15) * 4;
  for (int i = 0; i < 4; i++) {
    int r = i * 16 + tr;
    float4 val = *(const float4*)(w + (k0 + r) * Dd + n0 + tc);
    tile[r][tc + 0] = val.x; tile[r][tc + 1] = val.y;
    tile[r][tc + 2] = val.z; tile[r][tc + 3] = val.w;
  }
  __syncthreads();
  for (int i = 0; i < 2; i++) {
    int vdx = t + 256 * i;
    int rn = vdx >> 3;
    int c8 = (vdx & 7) * 8;
    union { f16x8 v8; _Float16 h[8]; } o2;
    for (int j = 0; j < 8; j++) o2.h[j] = (_Float16)(tile[c8 + j][rn] * wscale);
    *(f16x8*)(o + (n0 + rn) * Dd + k0 + c8) = o2.v8;
  }
}

// ---------------- K1: projection GEMM — double-buffered + XOR-swizzled LDS (r19, ~72us) ----------------
__global__ __launch_bounds__(256) void gemm_qkv(
    const float* __restrict__ aq, const float* __restrict__ ak,
    const float* __restrict__ av,
    const _Float16* __restrict__ wtq, const _Float16* __restrict__ wtk,
    const _Float16* __restrict__ wtv,
    const float* __restrict__ bq, const float* __restrict__ bk, const float* __restrict__ bv,
    _Float16* __restrict__ oq, _Float16* __restrict__ ok,
    _Float16* __restrict__ ov) {
  int z = blockIdx.z;
  const float* Af    = z == 0 ? aq  : (z == 1 ? ak  : av);
  const _Float16* Bt = z == 0 ? wtq : (z == 1 ? wtk : wtv);
  const float* bias  = z == 0 ? bq  : (z == 1 ? bk  : bv);
  _Float16* out      = z == 0 ? oq  : (z == 1 ? ok  : ov);
  float bscale       = z == 0 ? 1.4426950408889634f : 1.0f;

  __shared__ _Float16 As[2][128 * 64];
  __shared__ _Float16 Bs[2][128 * 64];

  int tid = threadIdx.x;
  int w = tid >> 6;
  int l = tid & 63;
  int lr = l & 15, lk = l >> 4;
  int m0 = blockIdx.x * 128;
  int n0 = blockIdx.y * 128;
  int wr = (w >> 1) * 64;
  int wc = (w & 1) * 64;

  int srow = l >> 3;
  int cs = (l & 7) ^ srow;
  const float*    ap[4];
  const _Float16* bp[4];
#pragma unroll
  for (int i = 0; i < 4; i++) {
    int row = i * 32 + w * 8 + srow;
    ap[i] = Af + (size_t)(m0 + row) * Dd + cs * 8;
    bp[i] = Bt + (size_t)(n0 + row) * Dd + cs * 8;
  }

  f32x4 acc[4][4] = {};
  int lr7 = lr & 7;
  int rs0 = (lk ^ lr7) * 8;
  int rs1 = ((4 + lk) ^ lr7) * 8;

#define ALOAD(AR)                                                         \
  _Pragma("unroll")                                                       \
  for (int i = 0; i < 4; i++) {                                           \
    AR[i][0] = *(const float4*)(ap[i]);                                   \
    AR[i][1] = *(const float4*)(ap[i] + 4);                               \
    ap[i] += 64;                                                          \
  }
#define BDMA(NXT)                                                         \
  _Pragma("unroll")                                                       \
  for (int i = 0; i < 4; i++) {                                           \
    gload16(bp[i], &Bs[NXT][(i * 256 + w * 64) * 8]);                     \
    bp[i] += 64;                                                          \
  }
#define AWRITE(AR, NXT)                                                   \
  _Pragma("unroll")                                                       \
  for (int i = 0; i < 4; i++) {                                           \
    union { unsigned u[4]; f16x8 v; } aw;                                 \
    aw.u[0] = pk2u(AR[i][0].x, AR[i][0].y);                               \
    aw.u[1] = pk2u(AR[i][0].z, AR[i][0].w);                               \
    aw.u[2] = pk2u(AR[i][1].x, AR[i][1].y);                               \
    aw.u[3] = pk2u(AR[i][1].z, AR[i][1].w);                               \
    *(f16x8*)&As[NXT][(i * 256 + w * 64 + l) * 8] = aw.v;                 \
  }
#define GCOMP(CUR)                                                              \
  _Pragma("unroll")                                                             \
  for (int kh = 0; kh < 2; kh++) {                                              \
    int rs = kh ? rs1 : rs0;                                                    \
    f16x8 af[4], bf[4];                                                         \
    _Pragma("unroll")                                                           \
    for (int mi = 0; mi < 4; mi++)                                              \
      af[mi] = *(const f16x8*)&As[CUR][(wr + mi * 16 + lr) * 64 + rs];          \
    _Pragma("unroll")                                                           \
    for (int ni = 0; ni < 4; ni++)                                              \
      bf[ni] = *(const f16x8*)&Bs[CUR][(wc + ni * 16 + lr) * 64 + rs];          \
    _Pragma("unroll")                                                           \
    for (int mi = 0; mi < 4; mi++)                                              \
      _Pragma("unroll")                                                         \
      for (int ni = 0; ni < 4; ni++)                                            \
        acc[mi][ni] = __builtin_amdgcn_mfma_f32_16x16x32_f16(af[mi], bf[ni], acc[mi][ni], 0, 0, 0); \
  }

  {
    float4 ar[4][2];
    ALOAD(ar)
    BDMA(0)
    AWRITE(ar, 0)
  }
  __syncthreads();

  for (int it = 0; it < 7; ++it) {
    {
      float4 ar[4][2];
      ALOAD(ar)
      BDMA(1)
      GCOMP(0)
      AWRITE(ar, 1)
    }
    __syncthreads();
    {
      float4 ar[4][2];
      ALOAD(ar)
      BDMA(0)
      GCOMP(1)
      AWRITE(ar, 0)
    }
    __syncthreads();
  }
  {
    float4 ar[4][2];
    ALOAD(ar)
    BDMA(1)
    GCOMP(0)
    AWRITE(ar, 1)
  }
  __syncthreads();
  GCOMP(1)
#undef GCOMP
#undef AWRITE
#undef BDMA
#undef ALOAD

  if (z == 2) {
    for (int mi = 0; mi < 4; mi++) {
      for (int ni = 0; ni < 4; ni++) {
        int n = n0 + wc + ni * 16 + lr;
        float bval = bias[n];
        int h = n >> 6, dk = n & 63;
        int m = m0 + wr + mi * 16 + lk * 4;
        int b = m >> 11, s = m & 2047;
        f16x4 o4;
        for (int j = 0; j < 4; j++) o4[j] = (_Float16)(acc[mi][ni][j] + bval);
        *(f16x4*)(out + ((size_t)((b * Hh + h) * DK + dk) * Ss + s)) = o4;
      }
    }
  } else {
    for (int mi = 0; mi < 4; mi++) {
      for (int ni = 0; ni < 4; ni++) {
        int n = n0 + wc + ni * 16 + lr;
        float bval = bias[n] * bscale;
        int h = n >> 6, dk = n & 63;
        for (int j = 0; j < 4; j++) {
          int m = m0 + wr + mi * 16 + lk * 4 + j;
          int b = m >> 11, s = m & 2047;
          out[((b * Hh + h) * Ss + s) * DK + dk] = (_Float16)(acc[mi][ni][j] + bval);
        }
      }
    }
  }
}

// ---------------- K3: flash attention — 4-wave blocks, 3-buffer LDS, counted-vmcnt barriers ----------------
// r17 math/layout exactly (121us known-good), with the ONE change: __syncthreads (full
// vmcnt(0) drain) -> raw s_barrier + counted vmcnt(4) (T3/T4). 3 LDS buffers (48KB) so the
// freshly-issued STAGE(t+2) stays in flight ACROSS the barrier; each wave drains only its
// own stage for the tile about to be consumed. qf loads drained (vmcnt(0)) before the
// pipeline so the manual ledger is exact (r9/r20 lesson: never mix untracked loads).
// Race screen: STAGE(t+2) writes buf (t-1)%3 whose readers finished before the previous
// barrier; TILE(t) reads a buffer own-drained at t-1 and barriered.
__global__ __launch_bounds__(256) void attn(const _Float16* __restrict__ Qb,
                                            const _Float16* __restrict__ Kb,
                                            const _Float16* __restrict__ Vt,
                                            const float* __restrict__ query,
                                            float* __restrict__ outp) {
  __shared__ _Float16 Kl[3][KVT * 64];
  __shared__ _Float16 Vl[3][KVT * 64];

  int tid = threadIdx.x;
  int w = tid >> 6, l = tid & 63;
  int l31 = l & 31, hi = l >> 5;
  int bh = blockIdx.x;
  int q0 = blockIdx.y * 128 + w * 32;
  const _Float16* Qp = Qb + bh * (Ss * DK);
  const _Float16* Kp = Kb + bh * (Ss * DK);
  const _Float16* Vp = Vt + bh * (DK * Ss);

  // staging: lane l -> row base+(l>>3), LDS slot l&7; global slot = (l&7)^(row&7)
  int srow = l >> 3;
  int sslot = (l & 7) ^ (srow & 7);
  int w16 = w * 16;
  const _Float16* kp0 = Kp + (w16 + srow) * DK + sslot * 8;
  const _Float16* kp1 = Kp + (w16 + 8 + srow) * DK + sslot * 8;
  const _Float16* vp0 = Vp + (w16 + srow) * Ss + sslot * 8;
  const _Float16* vp1 = Vp + (w16 + 8 + srow) * Ss + sslot * 8;

#define STAGE(BUF)                                                        \
  {                                                                       \
    gload16(kp0, &Kl[BUF][w16 * 64]);                                     \
    gload16(kp1, &Kl[BUF][(w16 + 8) * 64]);                               \
    gload16(vp0, &Vl[BUF][w16 * 64]);                                     \
    gload16(vp1, &Vl[BUF][(w16 + 8) * 64]);                               \
    kp0 += KVT * DK; kp1 += KVT * DK; vp0 += KVT; vp1 += KVT;             \
  }

  // Q as B-operand: col=q=q0+l31, k=dk=s*16+hi*8+i
  f16x8 qf[4];
#pragma unroll
  for (int s = 0; s < 4; s++)
    qf[s] = *(const f16x8*)(Qp + (q0 + l31) * DK + s * 16 + hi * 8);
  VW(0);          // qf in regs; VMEM ledger now exclusively DMA counts

  f32x16 o0 = {}, o1 = {};    // ctx^T: row d=dg*32+(r&3)+8*(r>>2)+4*hi, col q=l31
  float mrun = -1e30f, lrun = 0.f;   // lrun lane-partial

  int kv7 = l31 & 7;
  int rslot[4];
#pragma unroll
  for (int s = 0; s < 4; s++) rslot[s] = ((s * 2 + hi) ^ kv7) * 8;

#define PVSTEP(BUF, SRC, OFF, KST)                                              \
    {                                                                           \
      unsigned a0 = pk2u(SRC[(OFF) + 0], SRC[(OFF) + 1]);                       \
      unsigned a1 = pk2u(SRC[(OFF) + 2], SRC[(OFF) + 3]);                       \
      unsigned b0 = pk2u(SRC[(OFF) + 4], SRC[(OFF) + 5]);                       \
      unsigned b1 = pk2u(SRC[(OFF) + 6], SRC[(OFF) + 7]);                       \
      uint2v r0 = __builtin_amdgcn_permlane32_swap(a0, b0, false, false);       \
      uint2v r1 = __builtin_amdgcn_permlane32_swap(a1, b1, false, false);       \
      union { unsigned u[4]; f16x8 v; } pf;                                     \
      pf.u[0] = r0[0]; pf.u[1] = r1[0]; pf.u[2] = r0[1]; pf.u[3] = r1[1];       \
      f16x8 v0 = *(const f16x8*)&Vl[BUF][l31 * 64 + rslot[KST]];                \
      f16x8 v1 = *(const f16x8*)&Vl[BUF][(32 + l31) * 64 + rslot[KST]];         \
      o0 = __builtin_amdgcn_mfma_f32_32x32x16_f16(v0, pf.v, o0, 0, 0, 0);       \
      o1 = __builtin_amdgcn_mfma_f32_32x32x16_f16(v1, pf.v, o1, 0, 0, 0);       \
    }

#define TILE(BUF)                                                               \
  {                                                                             \
    f32x16 s0 = {}, s1 = {};                                                    \
    _Pragma("unroll")                                                           \
    for (int s = 0; s < 4; s++) {                                               \
      f16x8 ka = *(const f16x8*)&Kl[BUF][l31 * 64 + rslot[s]];                  \
      s0 = __builtin_amdgcn_mfma_f32_32x32x16_f16(ka, qf[s], s0, 0, 0, 0);      \
    }                                                                           \
    _Pragma("unroll")                                                           \
    for (int s = 0; s < 4; s++) {                                               \
      f16x8 kb = *(const f16x8*)&Kl[BUF][(32 + l31) * 64 + rslot[s]];           \
      s1 = __builtin_amdgcn_mfma_f32_32x32x16_f16(kb, qf[s], s1, 0, 0, 0);      \
    }                                                                           \
    float m8[8];                                                                \
    _Pragma("unroll")                                                           \
    for (int r = 0; r < 8; r++)                                                 \
      m8[r] = fmaxf(fmaxf(s0[r], s0[r + 8]), fmaxf(s1[r], s1[r + 8]));          \
    _Pragma("unroll")                                                           \
    for (int d = 4; d >= 1; d >>= 1)                                            \
      for (int r = 0; r < 4; r++) if (r < d) m8[r] = fmaxf(m8[r], m8[r + d]);   \
    float pm = xhalf_max(m8[0]);                                                \
    if (!__all(pm - mrun <= 8.f)) {   /* defer-max (T13), log2 units */         \
      float mn = fmaxf(mrun, pm);                                               \
      float sc_ = ex2(mrun - mn);                                               \
      mrun = mn;                                                                \
      lrun *= sc_;                                                              \
      _Pragma("unroll")                                                         \
      for (int r = 0; r < 16; r++) { o0[r] *= sc_; o1[r] *= sc_; }              \
    }                                                                           \
    _Pragma("unroll")                                                           \
    for (int r = 0; r < 16; r++) {                                              \
      s0[r] = ex2(s0[r] - mrun);                                                \
      s1[r] = ex2(s1[r] - mrun);                                                \
    }                                                                           \
    float s8[8];                                                                \
    _Pragma("unroll")                                                           \
    for (int r = 0; r < 8; r++) s8[r] = (s0[r] + s0[r + 8]) + (s1[r] + s1[r + 8]); \
    _Pragma("unroll")                                                           \
    for (int d = 4; d >= 1; d >>= 1)                                            \
      for (int r = 0; r < 4; r++) if (r < d) s8[r] += s8[r + d];                \
    lrun += s8[0];                                                              \
    PVSTEP(BUF, s0, 0, 0)                                                       \
    PVSTEP(BUF, s0, 8, 1)                                                       \
    PVSTEP(BUF, s1, 0, 2)                                                       \
    PVSTEP(BUF, s1, 8, 3)                                                       \
  }

  // prologue: stage tiles 0,1 (8 DMAs in flight); own stage0 done -> barrier
  STAGE(0)
  STAGE(1)
  VW(4);
  BAR();

  // steady: STAGE(t+2) || TILE(t), wait own stage(t+1), barrier. Tiles 0..29.
  for (int k = 0; k < 10; ++k) {
    STAGE(2)  TILE(0)  VW(4);  BAR();
    STAGE(0)  TILE(1)  VW(4);  BAR();
    STAGE(1)  TILE(2)  VW(4);  BAR();
  }
  // tail: tile 30 (buf0; staged at i=28, confirmed), then tile 31 (buf1)
  TILE(0)
  VW(0);
  BAR();
  TILE(1)
#undef TILE
#undef PVSTEP
#undef STAGE

  // ---- epilogue: reduce lane-partial lrun, normalize, add residual ----
  lrun += __shfl_xor(lrun, 32);
  int b = bh >> 4, h = bh & 15;
  float inv = 1.f / lrun;
  int base = (b * Ss + q0 + l31) * Dd + h * 64;
#pragma unroll
  for (int rq = 0; rq < 4; rq++) {
    int d0 = rq * 8 + hi * 4;
    float4 qv0 = *(const float4*)(query + base + d0);
    float4 ov0;
    ov0.x = o0[rq * 4 + 0] * inv + qv0.x;
    ov0.y = o0[rq * 4 + 1] * inv + qv0.y;
    ov0.z = o0[rq * 4 + 2] * inv + qv0.z;
    ov0.w = o0[rq * 4 + 3] * inv + qv0.w;
    *(float4*)(outp + base + d0) = ov0;
    float4 qv1 = *(const float4*)(query + base + 32 + d0);
    float4 ov1;
    ov1.x = o1[rq * 4 + 0] * inv + qv1.x;
    ov1.y = o1[rq * 4 + 1] * inv + qv1.y;
    ov1.z = o1[rq * 4 + 2] * inv + qv1.z;
    ov1.w = o1[rq * 4 + 3] * inv + qv1.w;
    *(float4*)(outp + base + 32 + d0) = ov1;
  }
}

extern "C" void kernel_launch(void* const* d_in, const int* in_sizes, int n_in,
                              void* d_out, int out_size, void* d_ws, size_t ws_size,
                              hipStream_t stream) {
  const float* query = (const float*)d_in[0];
  const float* key   = (const float*)d_in[1];
  const float* value = (const float*)d_in[2];
  const float* Wq = (const float*)d_in[3];
  const float* bq = (const float*)d_in[4];
  const float* Wk = (const float*)d_in[5];
  const float* bk = (const float*)d_in[6];
  const float* Wv = (const float*)d_in[7];
  const float* bv = (const float*)d_in[8];
  float* out = (float*)d_out;

  _Float16* ws = (_Float16*)d_ws;
  const size_t ACT = (size_t)Mm * Dd;
  const size_t WSZ = (size_t)Dd * Dd;
  _Float16* Wtq  = ws;
  _Float16* Wtk  = Wtq + WSZ;
  _Float16* Wtv  = Wtk + WSZ;
  _Float16* Qb   = Wtv + WSZ;
  _Float16* Kb   = Qb + ACT;
  _Float16* VtT  = Kb + ACT;   // gemm writes V^T [bh][dk][s] here directly

  cvt_wt<<<dim3(16, 16, 3), dim3(256), 0, stream>>>(Wq, Wk, Wv, Wtq, Wtk, Wtv);
  gemm_qkv<<<dim3(64, 8, 3), dim3(256), 0, stream>>>(query, key, value, Wtq, Wtk, Wtv,
                                                     bq, bk, bv, Qb, Kb, VtT);
  attn<<<dim3(64, 16), dim3(256), 0, stream>>>(Qb, Kb, VtT, query, out);
}

// Round 22
// 195.720 us; speedup vs baseline: 1.1757x; 1.0239x over previous
//
#include <hip/hip_runtime.h>
#include <hip/hip_bf16.h>
#include <stdint.h>

#define Bb 4
#define Ss 2048
#define Dd 1024
#define Hh 16
#define DK 64
#define BH 64
#define Mm 8192
#define KVT 64

typedef __attribute__((ext_vector_type(8))) _Float16 f16x8;
typedef __attribute__((ext_vector_type(4))) _Float16 f16x4;
typedef __attribute__((ext_vector_type(2))) __fp16 fp16x2;
typedef __attribute__((ext_vector_type(4))) float f32x4;
typedef __attribute__((ext_vector_type(16))) float f32x16;
typedef __attribute__((ext_vector_type(2))) unsigned uint2v;

__device__ __forceinline__ void gload16(const _Float16* g, _Float16* lds) {
  __builtin_amdgcn_global_load_lds((const __attribute__((address_space(1))) unsigned int*)g,
                                   (__attribute__((address_space(3))) unsigned int*)lds, 16, 0, 0);
}

// single v_exp_f32 (2^x). exp2f() is the libm path — the r11 regression.
#if __has_builtin(__builtin_amdgcn_exp2f)
__device__ __forceinline__ float ex2(float x) { return __builtin_amdgcn_exp2f(x); }
#else
__device__ __forceinline__ float ex2(float x) {
  float r; asm("v_exp_f32 %0, %1" : "=v"(r) : "v"(x)); return r;
}
#endif

// pack two f32 -> u32 of 2 f16 (v_cvt_pkrtz_f16_f32, 1 inst)
__device__ __forceinline__ unsigned pk2u(float a, float b) {
  union { fp16x2 h; unsigned u; } x;
  x.h = __builtin_amdgcn_cvt_pkrtz(a, b);
  return x.u;
}

// cross-half (lane ^ 32) max via permlane32_swap (VALU, not ds_bpermute)
__device__ __forceinline__ float xhalf_max(float x) {
  union { float f; unsigned u; } a; a.f = x;
  uint2v r = __builtin_amdgcn_permlane32_swap(a.u, a.u, false, false);
  union { unsigned u; float f; } b0, b1; b0.u = r[0]; b1.u = r[1];
  return fmaxf(fmaxf(x, b0.f), b1.f);
}

// ---------------- K0b: convert + transpose weights: Wt[n][k] = f16(W[k][n]) ----------------
// Q weights pre-scaled by log2(e): attention scores land in the exp2 domain.
__global__ __launch_bounds__(256) void cvt_wt(const float* __restrict__ wq,
                                              const float* __restrict__ wk,
                                              const float* __restrict__ wv,
                                              _Float16* __restrict__ tq,
                                              _Float16* __restrict__ tk,
                                              _Float16* __restrict__ tv) {
  const float* w = blockIdx.z == 0 ? wq : (blockIdx.z == 1 ? wk : wv);
  _Float16* o = blockIdx.z == 0 ? tq : (blockIdx.z == 1 ? tk : tv);
  float wscale = blockIdx.z == 0 ? 1.4426950408889634f : 1.0f;
  __shared__ float tile[64][65];
  int k0 = blockIdx.x * 64;
  int n0 = blockIdx.y * 64;
  int t = threadIdx.x;
  int tr = t >> 4;
  int tc = (t & 15) * 4;
  for (int i = 0; i < 4; i++) {
    int r = i * 16 + tr;
    float4 val = *(const float4*)(w + (k0 + r) * Dd + n0 + tc);
    tile[r][tc + 0] = val.x; tile[r][tc + 1] = val.y;
    tile[r][tc + 2] = val.z; tile[r][tc + 3] = val.w;
  }
  __syncthreads();
  for (int i = 0; i < 2; i++) {
    int vdx = t + 256 * i;
    int rn = vdx >> 3;
    int c8 = (vdx & 7) * 8;
    union { f16x8 v8; _Float16 h[8]; } o2;
    for (int j = 0; j < 8; j++) o2.h[j] = (_Float16)(tile[c8 + j][rn] * wscale);
    *(f16x8*)(o + (n0 + rn) * Dd + k0 + c8) = o2.v8;
  }
}

// ---------------- K1: projection GEMM — double-buffered + XOR-swizzled LDS (r19, ~72us) ----------------
__global__ __launch_bounds__(256) void gemm_qkv(
    const float* __restrict__ aq, const float* __restrict__ ak,
    const float* __restrict__ av,
    const _Float16* __restrict__ wtq, const _Float16* __restrict__ wtk,
    const _Float16* __restrict__ wtv,
    const float* __restrict__ bq, const float* __restrict__ bk, const float* __restrict__ bv,
    _Float16* __restrict__ oq, _Float16* __restrict__ ok,
    _Float16* __restrict__ ov) {
  int z = blockIdx.z;
  const float* Af    = z == 0 ? aq  : (z == 1 ? ak  : av);
  const _Float16* Bt = z == 0 ? wtq : (z == 1 ? wtk : wtv);
  const float* bias  = z == 0 ? bq  : (z == 1 ? bk  : bv);
  _Float16* out      = z == 0 ? oq  : (z == 1 ? ok  : ov);
  float bscale       = z == 0 ? 1.4426950408889634f : 1.0f;

  __shared__ _Float16 As[2][128 * 64];
  __shared__ _Float16 Bs[2][128 * 64];

  int tid = threadIdx.x;
  int w = tid >> 6;
  int l = tid & 63;
  int lr = l & 15, lk = l >> 4;
  int m0 = blockIdx.x * 128;
  int n0 = blockIdx.y * 128;
  int wr = (w >> 1) * 64;
  int wc = (w & 1) * 64;

  int srow = l >> 3;
  int cs = (l & 7) ^ srow;
  const float*    ap[4];
  const _Float16* bp[4];
#pragma unroll
  for (int i = 0; i < 4; i++) {
    int row = i * 32 + w * 8 + srow;
    ap[i] = Af + (size_t)(m0 + row) * Dd + cs * 8;
    bp[i] = Bt + (size_t)(n0 + row) * Dd + cs * 8;
  }

  f32x4 acc[4][4] = {};
  int lr7 = lr & 7;
  int rs0 = (lk ^ lr7) * 8;
  int rs1 = ((4 + lk) ^ lr7) * 8;

#define ALOAD(AR)                                                         \
  _Pragma("unroll")                                                       \
  for (int i = 0; i < 4; i++) {                                           \
    AR[i][0] = *(const float4*)(ap[i]);                                   \
    AR[i][1] = *(const float4*)(ap[i] + 4);                               \
    ap[i] += 64;                                                          \
  }
#define BDMA(NXT)                                                         \
  _Pragma("unroll")                                                       \
  for (int i = 0; i < 4; i++) {                                           \
    gload16(bp[i], &Bs[NXT][(i * 256 + w * 64) * 8]);                     \
    bp[i] += 64;                                                          \
  }
#define AWRITE(AR, NXT)                                                   \
  _Pragma("unroll")                                                       \
  for (int i = 0; i < 4; i++) {                                           \
    union { unsigned u[4]; f16x8 v; } aw;                                 \
    aw.u[0] = pk2u(AR[i][0].x, AR[i][0].y);                               \
    aw.u[1] = pk2u(AR[i][0].z, AR[i][0].w);                               \
    aw.u[2] = pk2u(AR[i][1].x, AR[i][1].y);                               \
    aw.u[3] = pk2u(AR[i][1].z, AR[i][1].w);                               \
    *(f16x8*)&As[NXT][(i * 256 + w * 64 + l) * 8] = aw.v;                 \
  }
#define GCOMP(CUR)                                                              \
  _Pragma("unroll")                                                             \
  for (int kh = 0; kh < 2; kh++) {                                              \
    int rs = kh ? rs1 : rs0;                                                    \
    f16x8 af[4], bf[4];                                                         \
    _Pragma("unroll")                                                           \
    for (int mi = 0; mi < 4; mi++)                                              \
      af[mi] = *(const f16x8*)&As[CUR][(wr + mi * 16 + lr) * 64 + rs];          \
    _Pragma("unroll")                                                           \
    for (int ni = 0; ni < 4; ni++)                                              \
      bf[ni] = *(const f16x8*)&Bs[CUR][(wc + ni * 16 + lr) * 64 + rs];          \
    _Pragma("unroll")                                                           \
    for (int mi = 0; mi < 4; mi++)                                              \
      _Pragma("unroll")                                                         \
      for (int ni = 0; ni < 4; ni++)                                            \
        acc[mi][ni] = __builtin_amdgcn_mfma_f32_16x16x32_f16(af[mi], bf[ni], acc[mi][ni], 0, 0, 0); \
  }

  {
    float4 ar[4][2];
    ALOAD(ar)
    BDMA(0)
    AWRITE(ar, 0)
  }
  __syncthreads();

  for (int it = 0; it < 7; ++it) {
    {
      float4 ar[4][2];
      ALOAD(ar)
      BDMA(1)
      GCOMP(0)
      AWRITE(ar, 1)
    }
    __syncthreads();
    {
      float4 ar[4][2];
      ALOAD(ar)
      BDMA(0)
      GCOMP(1)
      AWRITE(ar, 0)
    }
    __syncthreads();
  }
  {
    float4 ar[4][2];
    ALOAD(ar)
    BDMA(1)
    GCOMP(0)
    AWRITE(ar, 1)
  }
  __syncthreads();
  GCOMP(1)
#undef GCOMP
#undef AWRITE
#undef BDMA
#undef ALOAD

  if (z == 2) {
    for (int mi = 0; mi < 4; mi++) {
      for (int ni = 0; ni < 4; ni++) {
        int n = n0 + wc + ni * 16 + lr;
        float bval = bias[n];
        int h = n >> 6, dk = n & 63;
        int m = m0 + wr + mi * 16 + lk * 4;
        int b = m >> 11, s = m & 2047;
        f16x4 o4;
        for (int j = 0; j < 4; j++) o4[j] = (_Float16)(acc[mi][ni][j] + bval);
        *(f16x4*)(out + ((size_t)((b * Hh + h) * DK + dk) * Ss + s)) = o4;
      }
    }
  } else {
    for (int mi = 0; mi < 4; mi++) {
      for (int ni = 0; ni < 4; ni++) {
        int n = n0 + wc + ni * 16 + lr;
        float bval = bias[n] * bscale;
        int h = n >> 6, dk = n & 63;
        for (int j = 0; j < 4; j++) {
          int m = m0 + wr + mi * 16 + lk * 4 + j;
          int b = m >> 11, s = m & 2047;
          out[((b * Hh + h) * Ss + s) * DK + dk] = (_Float16)(acc[mi][ni][j] + bval);
        }
      }
    }
  }
}

// ---------------- K3: flash attention, 32x32x16, LDS dbuf K/V, kv-loop unrolled x2 (r17, 121us) ----------------
__global__ __launch_bounds__(256) void attn(const _Float16* __restrict__ Qb,
                                            const _Float16* __restrict__ Kb,
                                            const _Float16* __restrict__ Vt,
                                            const float* __restrict__ query,
                                            float* __restrict__ outp) {
  __shared__ _Float16 Kl[2][KVT * 64];
  __shared__ _Float16 Vl[2][KVT * 64];

  int tid = threadIdx.x;
  int w = tid >> 6, l = tid & 63;
  int l31 = l & 31, hi = l >> 5;
  int bh = blockIdx.x;
  int q0 = blockIdx.y * 128 + w * 32;
  const _Float16* Qp = Qb + bh * (Ss * DK);
  const _Float16* Kp = Kb + bh * (Ss * DK);
  const _Float16* Vp = Vt + bh * (DK * Ss);

  // staging: lane l -> row base+(l>>3), LDS slot l&7; global slot = (l&7)^(row&7)
  int srow = l >> 3;
  int sslot = (l & 7) ^ (srow & 7);
  int w16 = w * 16;
  // running stage pointers (strength-reduced; advanced after each STAGE)
  const _Float16* kp0 = Kp + (w16 + srow) * DK + sslot * 8;
  const _Float16* kp1 = Kp + (w16 + 8 + srow) * DK + sslot * 8;
  const _Float16* vp0 = Vp + (w16 + srow) * Ss + sslot * 8;
  const _Float16* vp1 = Vp + (w16 + 8 + srow) * Ss + sslot * 8;

#define STAGE(BUF)                                                        \
  {                                                                       \
    gload16(kp0, &Kl[BUF][w16 * 64]);                                     \
    gload16(kp1, &Kl[BUF][(w16 + 8) * 64]);                               \
    gload16(vp0, &Vl[BUF][w16 * 64]);                                     \
    gload16(vp1, &Vl[BUF][(w16 + 8) * 64]);                               \
    kp0 += KVT * DK; kp1 += KVT * DK; vp0 += KVT; vp1 += KVT;             \
  }

  // Q as B-operand: col=q=q0+l31, k=dk=s*16+hi*8+i
  f16x8 qf[4];
#pragma unroll
  for (int s = 0; s < 4; s++)
    qf[s] = *(const f16x8*)(Qp + (q0 + l31) * DK + s * 16 + hi * 8);

  f32x16 o0 = {}, o1 = {};    // ctx^T: row d=dg*32+(r&3)+8*(r>>2)+4*hi, col q=l31
  float mrun = -1e30f, lrun = 0.f;   // lrun is LANE-PARTIAL (this half's sum)

  // swizzled LDS read slots: slot = ((s*2+hi) ^ (row&7)), row&7 == l31&7 for our reads
  int kv7 = l31 & 7;
  int rslot[4];
#pragma unroll
  for (int s = 0; s < 4; s++) rslot[s] = ((s * 2 + hi) ^ kv7) * 8;

  // TILE: full per-tile compute on compile-time buffer BUF
#define TILE(BUF)                                                               \
  {                                                                             \
    f32x16 s0 = {}, s1 = {};                                                    \
    _Pragma("unroll")                                                           \
    for (int s = 0; s < 4; s++) {                                               \
      f16x8 ka = *(const f16x8*)&Kl[BUF][l31 * 64 + rslot[s]];                  \
      s0 = __builtin_amdgcn_mfma_f32_32x32x16_f16(ka, qf[s], s0, 0, 0, 0);      \
    }                                                                           \
    _Pragma("unroll")                                                           \
    for (int s = 0; s < 4; s++) {                                               \
      f16x8 kb = *(const f16x8*)&Kl[BUF][(32 + l31) * 64 + rslot[s]];           \
      s1 = __builtin_amdgcn_mfma_f32_32x32x16_f16(kb, qf[s], s1, 0, 0, 0);      \
    }                                                                           \
    float m8[8];                                                                \
    _Pragma("unroll")                                                           \
    for (int r = 0; r < 8; r++)                                                 \
      m8[r] = fmaxf(fmaxf(s0[r], s0[r + 8]), fmaxf(s1[r], s1[r + 8]));          \
    _Pragma("unroll")                                                           \
    for (int d = 4; d >= 1; d >>= 1)                                            \
      for (int r = 0; r < 4; r++) if (r < d) m8[r] = fmaxf(m8[r], m8[r + d]);   \
    float pm = xhalf_max(m8[0]);                                                \
    if (!__all(pm - mrun <= 8.f)) {   /* defer-max (T13), log2 units */         \
      float mn = fmaxf(mrun, pm);                                               \
      float sc_ = ex2(mrun - mn);                                               \
      mrun = mn;                                                                \
      lrun *= sc_;                                                              \
      _Pragma("unroll")                                                         \
      for (int r = 0; r < 16; r++) { o0[r] *= sc_; o1[r] *= sc_; }              \
    }                                                                           \
    _Pragma("unroll")                                                           \
    for (int r = 0; r < 16; r++) {                                              \
      s0[r] = ex2(s0[r] - mrun);                                                \
      s1[r] = ex2(s1[r] - mrun);                                                \
    }                                                                           \
    float s8[8];                                                                \
    _Pragma("unroll")                                                           \
    for (int r = 0; r < 8; r++) s8[r] = (s0[r] + s0[r + 8]) + (s1[r] + s1[r + 8]); \
    _Pragma("unroll")                                                           \
    for (int d = 4; d >= 1; d >>= 1)                                            \
      for (int r = 0; r < 4; r++) if (r < d) s8[r] += s8[r + d];                \
    lrun += s8[0];                                                              \
    PVSTEP(BUF, s0, 0, 0)                                                       \
    PVSTEP(BUF, s0, 8, 1)                                                       \
    PVSTEP(BUF, s1, 0, 2)                                                       \
    PVSTEP(BUF, s1, 8, 3)                                                       \
  }

#define PVSTEP(BUF, SRC, OFF, KST)                                              \
    {                                                                           \
      unsigned a0 = pk2u(SRC[(OFF) + 0], SRC[(OFF) + 1]);                       \
      unsigned a1 = pk2u(SRC[(OFF) + 2], SRC[(OFF) + 3]);                       \
      unsigned b0 = pk2u(SRC[(OFF) + 4], SRC[(OFF) + 5]);                       \
      unsigned b1 = pk2u(SRC[(OFF) + 6], SRC[(OFF) + 7]);                       \
      uint2v r0 = __builtin_amdgcn_permlane32_swap(a0, b0, false, false);       \
      uint2v r1 = __builtin_amdgcn_permlane32_swap(a1, b1, false, false);       \
      union { unsigned u[4]; f16x8 v; } pf;                                     \
      pf.u[0] = r0[0]; pf.u[1] = r1[0]; pf.u[2] = r0[1]; pf.u[3] = r1[1];       \
      f16x8 v0 = *(const f16x8*)&Vl[BUF][l31 * 64 + rslot[KST]];                \
      f16x8 v1 = *(const f16x8*)&Vl[BUF][(32 + l31) * 64 + rslot[KST]];         \
      o0 = __builtin_amdgcn_mfma_f32_32x32x16_f16(v0, pf.v, o0, 0, 0, 0);       \
      o1 = __builtin_amdgcn_mfma_f32_32x32x16_f16(v1, pf.v, o1, 0, 0, 0);       \
    }

  STAGE(0)
  __syncthreads();

  // 15 double-tiles with full prefetch, then the final pair (no stage past end)
  for (int it = 0; it < 15; ++it) {
    STAGE(1)
    TILE(0)
    __syncthreads();
    STAGE(0)
    TILE(1)
    __syncthreads();
  }
  STAGE(1)
  TILE(0)
  __syncthreads();
  TILE(1)
#undef PVSTEP
#undef TILE
#undef STAGE

  // ---- epilogue: reduce lane-partial lrun, normalize, add residual ----
  lrun += __shfl_xor(lrun, 32);
  int b = bh >> 4, h = bh & 15;
  float inv = 1.f / lrun;
  int base = (b * Ss + q0 + l31) * Dd + h * 64;
#pragma unroll
  for (int rq = 0; rq < 4; rq++) {
    int d0 = rq * 8 + hi * 4;
    float4 qv0 = *(const float4*)(query + base + d0);
    float4 ov0;
    ov0.x = o0[rq * 4 + 0] * inv + qv0.x;
    ov0.y = o0[rq * 4 + 1] * inv + qv0.y;
    ov0.z = o0[rq * 4 + 2] * inv + qv0.z;
    ov0.w = o0[rq * 4 + 3] * inv + qv0.w;
    *(float4*)(outp + base + d0) = ov0;
    float4 qv1 = *(const float4*)(query + base + 32 + d0);
    float4 ov1;
    ov1.x = o1[rq * 4 + 0] * inv + qv1.x;
    ov1.y = o1[rq * 4 + 1] * inv + qv1.y;
    ov1.z = o1[rq * 4 + 2] * inv + qv1.z;
    ov1.w = o1[rq * 4 + 3] * inv + qv1.w;
    *(float4*)(outp + base + 32 + d0) = ov1;
  }
}

extern "C" void kernel_launch(void* const* d_in, const int* in_sizes, int n_in,
                              void* d_out, int out_size, void* d_ws, size_t ws_size,
                              hipStream_t stream) {
  const float* query = (const float*)d_in[0];
  const float* key   = (const float*)d_in[1];
  const float* value = (const float*)d_in[2];
  const float* Wq = (const float*)d_in[3];
  const float* bq = (const float*)d_in[4];
  const float* Wk = (const float*)d_in[5];
  const float* bk = (const float*)d_in[6];
  const float* Wv = (const float*)d_in[7];
  const float* bv = (const float*)d_in[8];
  float* out = (float*)d_out;

  _Float16* ws = (_Float16*)d_ws;
  const size_t ACT = (size_t)Mm * Dd;
  const size_t WSZ = (size_t)Dd * Dd;
  _Float16* Wtq  = ws;
  _Float16* Wtk  = Wtq + WSZ;
  _Float16* Wtv  = Wtk + WSZ;
  _Float16* Qb   = Wtv + WSZ;
  _Float16* Kb   = Qb + ACT;
  _Float16* VtT  = Kb + ACT;   // gemm writes V^T [bh][dk][s] here directly

  cvt_wt<<<dim3(16, 16, 3), dim3(256), 0, stream>>>(Wq, Wk, Wv, Wtq, Wtk, Wtv);
  gemm_qkv<<<dim3(64, 8, 3), dim3(256), 0, stream>>>(query, key, value, Wtq, Wtk, Wtv,
                                                     bq, bk, bv, Qb, Kb, VtT);
  attn<<<dim3(64, 16), dim3(256), 0, stream>>>(Qb, Kb, VtT, query, out);
}